// Round 8
// baseline (177.750 us; speedup 1.0000x reference)
//
#include <hip/hip_runtime.h>
#include <cstdint>
#include <cstddef>

// CausalSelfAttention MI355X (gfx950). fp32 I/O, bf16 MFMA compute, fp32 accum.
// B=2, T=2048, C=1024, H=16, Dh=64.
// [cast f32->bf16 + device rope-table] -> [QKV gemm: 256x256 8-phase template,
// fused rmsnorm+rope epilogue; q pre-scaled by 0.125*log2(e)] -> [flash
// attention: KEY-SPLIT waves. QBLK=64, 4 waves; wave w owns keys w*16..+15 ->
// per step reads only 2 K-b128 + 4 V-b64 from LDS (4x less than q-split);
// ALL Q fragments held in registers (loaded once); P in-register (mfma16 PV,
// round-7 verified); o = full 64x64 key-partial per wave, cross-wave LDS tree
// reduction ONCE per block. K/V staged via global_load_lds (source-XOR
// swizzle, linear dest; __syncthreads drains vmcnt). softmax: exp2(S) with
// scale folded into Q, no static-max shift (S<=8 bounded by rmsnorm).] ->
// [gemm proj (m97)].
// Lessons: never dyn-index reg arrays; never global-gather K/V fragments.

typedef short bf16x8 __attribute__((ext_vector_type(8)));
typedef short bf16x4 __attribute__((ext_vector_type(4)));
typedef float floatx4 __attribute__((ext_vector_type(4)));
typedef float floatx2 __attribute__((ext_vector_type(2)));
typedef unsigned short ushortx8 __attribute__((ext_vector_type(8)));
typedef unsigned short ushortx4 __attribute__((ext_vector_type(4)));
typedef unsigned int uintx2 __attribute__((ext_vector_type(2)));

#define DEVI __device__ __forceinline__

DEVI unsigned short f2bf(float f) {
    unsigned int u = __builtin_bit_cast(unsigned int, f);
    u += 0x7fffu + ((u >> 16) & 1u);   // RNE; finite values only
    return (unsigned short)(u >> 16);
}
// pack 2 fp32 -> 2 bf16 in one dword: low16=bf(a), high16=bf(b) (inputs >= 0)
DEVI unsigned int pkbf2(float a, float b) {
    unsigned int ua = __builtin_bit_cast(unsigned int, a) + 0x8000u;
    unsigned int ub = __builtin_bit_cast(unsigned int, b) + 0x8000u;
    return __builtin_amdgcn_perm(ub, ua, 0x07060302);
}

// async global->LDS, 16B per lane; LDS dest = wave-uniform base + lane*16.
DEVI void glds16(const unsigned short* g, unsigned short* l) {
    __builtin_amdgcn_global_load_lds(
        (const __attribute__((address_space(1))) unsigned int*)g,
        (__attribute__((address_space(3))) unsigned int*)l, 16, 0, 0);
}

DEVI void cast8(unsigned short* dst, const float* src) {
    floatx4 a = *(const floatx4*)src;
    floatx4 b = *(const floatx4*)(src + 4);
    ushortx8 o;
    o[0] = f2bf(a[0]); o[1] = f2bf(a[1]); o[2] = f2bf(a[2]); o[3] = f2bf(a[3]);
    o[4] = f2bf(b[0]); o[5] = f2bf(b[1]); o[6] = f2bf(b[2]); o[7] = f2bf(b[3]);
    *(ushortx8*)dst = o;
}

// ---------------------------------------------------------------------------
__global__ __launch_bounds__(256)
void cast_inputs(const float* __restrict__ x, const float* __restrict__ wa,
                 const float* __restrict__ wp,
                 unsigned short* __restrict__ xb, unsigned short* __restrict__ wab,
                 unsigned short* __restrict__ wpb, float* __restrict__ ropetab)
{
    size_t g = (size_t)blockIdx.x * 256 + threadIdx.x;
    size_t stride = (size_t)gridDim.x * 256;
    for (size_t i = g; i < (4194304 / 8); i += stride) cast8(xb  + i * 8, x  + i * 8);
    for (size_t i = g; i < (3145728 / 8); i += stride) cast8(wab + i * 8, wa + i * 8);
    for (size_t i = g; i < (1048576 / 8); i += stride) cast8(wpb + i * 8, wp + i * 8);
    // rope table: [t=0..2047][f=0..31] -> (cos, sin) of t * 1e4^(-f/32).
    for (size_t i = g; i < 65536; i += stride) {
        int t = (int)(i >> 5), f = (int)(i & 31);
        float ang = (float)t * __expf(-(float)f * 0.28782313662425572f); // ln(1e4)/32
        float sn, cs;
        __sincosf(ang, &sn, &cs);
        ropetab[2 * i]     = cs;
        ropetab[2 * i + 1] = sn;
    }
}

// ---------------------------------------------------------------------------
// QKV GEMM, 8-phase 256^2 template. C[M=4096,N=3072] = A[M,1024] @ B[N,1024]^T.
// ---------------------------------------------------------------------------
__global__ __launch_bounds__(512, 2)
void gemm_qkv_8ph(const unsigned short* __restrict__ A,
                  const unsigned short* __restrict__ B,
                  const float* __restrict__ ropetab,
                  unsigned short* __restrict__ Cqk,
                  unsigned short* __restrict__ Vt)
{
    __shared__ __align__(16) unsigned short lds[2][2][256 * 64]; // [buf][A/B][..] 128KiB

    const int tid  = threadIdx.x;
    const int lane = tid & 63;
    const int w    = tid >> 6;         // 0..7
    const int wm   = w >> 2;           // 0..1 (output row half)
    const int wn   = w & 3;            // 0..3 (output col quarter = one head)
    const int quad = lane >> 4;
    const int lm   = lane & 15;

    // bijective XCD swizzle (192 blocks, 192 % 8 == 0)
    const int lin = blockIdx.y * 12 + blockIdx.x;
    const int s   = (lin & 7) * 24 + (lin >> 3);
    const int m0  = (s / 12) * 256;
    const int n0  = (s % 12) * 256;

    const int srow = tid >> 3;                                       // 0..63
    const int scol = (((tid & 7) ^ ((tid >> 3) & 7)) * 8);           // pre-swizzled
    const int ldst = w * 512;                                        // wave LDS base

#define STG_A(u, WBi, kq) glds16(&A[(size_t)(m0 + (u) * 64 + srow) * 1024 + (kq) + scol], \
                                 &lds[WBi][0][(u) * 4096 + ldst])
#define STG_B(u, WBi, kq) glds16(&B[(size_t)(n0 + (u) * 64 + srow) * 1024 + (kq) + scol], \
                                 &lds[WBi][1][(u) * 4096 + ldst])
#define RD_A(RBi, rrow, kk) (*(const bf16x8*)&lds[RBi][0][(rrow) * 64 + ((((kk) * 4 + quad) ^ ((rrow) & 7)) * 8)])
#define RD_B(RBi, rrow, kk) (*(const bf16x8*)&lds[RBi][1][(rrow) * 64 + ((((kk) * 4 + quad) ^ ((rrow) & 7)) * 8)])

    floatx4 acc[8][4] = {};
    bf16x8 afr[4][2];
    bf16x8 bfr[4][2];

#define MQ(MB, JB)                                                              \
  do {                                                                          \
    _Pragma("unroll")                                                           \
    for (int kk = 0; kk < 2; ++kk)                                              \
      _Pragma("unroll")                                                         \
      for (int mi = 0; mi < 4; ++mi)                                            \
        _Pragma("unroll")                                                       \
        for (int j2 = 0; j2 < 2; ++j2)                                          \
          acc[(MB) + mi][(JB) + j2] = __builtin_amdgcn_mfma_f32_16x16x32_bf16(  \
              afr[mi][kk], bfr[(JB) + j2][kk], acc[(MB) + mi][(JB) + j2], 0, 0, 0); \
  } while (0)

#define TILE(RBi, WBi, KT, LASTF)                                               \
  do {                                                                          \
    const int kn = ((KT) + 1) * 64;                                             \
    if (!(LASTF)) { STG_B(0, WBi, kn); STG_B(1, WBi, kn); }                     \
    _Pragma("unroll")                                                           \
    for (int kk = 0; kk < 2; ++kk) {                                            \
      _Pragma("unroll")                                                         \
      for (int mi = 0; mi < 4; ++mi)                                            \
        afr[mi][kk] = RD_A(RBi, wm * 128 + mi * 16 + lm, kk);                   \
      _Pragma("unroll")                                                         \
      for (int j2 = 0; j2 < 2; ++j2)                                            \
        bfr[j2][kk] = RD_B(RBi, wn * 64 + j2 * 16 + lm, kk);                    \
    }                                                                           \
    asm volatile("s_waitcnt lgkmcnt(8)" ::: "memory");                          \
    __builtin_amdgcn_s_barrier();                                               \
    asm volatile("s_waitcnt lgkmcnt(0)" ::: "memory");                          \
    __builtin_amdgcn_s_setprio(1); MQ(0, 0); __builtin_amdgcn_s_setprio(0);     \
    __builtin_amdgcn_s_barrier();                                               \
    if (!(LASTF)) { STG_B(2, WBi, kn); STG_B(3, WBi, kn); }                     \
    _Pragma("unroll")                                                           \
    for (int kk = 0; kk < 2; ++kk)                                              \
      _Pragma("unroll")                                                         \
      for (int j2 = 0; j2 < 2; ++j2)                                            \
        bfr[2 + j2][kk] = RD_B(RBi, wn * 64 + (2 + j2) * 16 + lm, kk);          \
    if (!(LASTF)) { asm volatile("s_waitcnt vmcnt(4)" ::: "memory"); }          \
    else          { asm volatile("s_waitcnt vmcnt(0)" ::: "memory"); }          \
    __builtin_amdgcn_s_barrier();                                               \
    asm volatile("s_waitcnt lgkmcnt(0)" ::: "memory");                          \
    __builtin_amdgcn_s_setprio(1); MQ(0, 2); __builtin_amdgcn_s_setprio(0);     \
    __builtin_amdgcn_s_barrier();                                               \
    if (!(LASTF)) { STG_A(0, WBi, kn); STG_A(2, WBi, kn); }                     \
    _Pragma("unroll")                                                           \
    for (int kk = 0; kk < 2; ++kk)                                              \
      _Pragma("unroll")                                                         \
      for (int mi = 0; mi < 4; ++mi)                                            \
        afr[mi][kk] = RD_A(RBi, wm * 128 + 64 + mi * 16 + lm, kk);              \
    __builtin_amdgcn_s_barrier();                                               \
    asm volatile("s_waitcnt lgkmcnt(0)" ::: "memory");                          \
    __builtin_amdgcn_s_setprio(1); MQ(4, 2); __builtin_amdgcn_s_setprio(0);     \
    __builtin_amdgcn_s_barrier();                                               \
    if (!(LASTF)) { STG_A(1, WBi, kn); STG_A(3, WBi, kn);                       \
                    asm volatile("s_waitcnt vmcnt(2)" ::: "memory"); }          \
    __builtin_amdgcn_s_barrier();                                               \
    __builtin_amdgcn_s_setprio(1); MQ(4, 0); __builtin_amdgcn_s_setprio(0);     \
    __builtin_amdgcn_s_barrier();                                               \
  } while (0)

    STG_B(0, 0, 0); STG_B(1, 0, 0); STG_B(2, 0, 0); STG_B(3, 0, 0);
    STG_A(0, 0, 0); STG_A(2, 0, 0); STG_A(1, 0, 0); STG_A(3, 0, 0);
    asm volatile("s_waitcnt vmcnt(2)" ::: "memory");
    __builtin_amdgcn_s_barrier();

    for (int kt = 0; kt < 14; kt += 2) {
        TILE(0, 1, kt, false);
        TILE(1, 0, kt + 1, false);
    }
    TILE(0, 1, 14, false);
    TILE(1, 0, 15, true);

    // -------- fused epilogue: RMSNorm + RoPE via precomputed table --------
    // q (cols < 1024) additionally scaled by 0.125*log2(e) so attention can
    // use exp2(S) directly (softmax scale folded into Q).
    const bool is_v = (n0 + wn * 64) >= 2048;   // wave-uniform; one head per wave
    if (!is_v) {
        const float qsc = ((n0 + wn * 64) < 1024) ? 0.18033688011112043f : 1.0f;
        const floatx2* rtab = (const floatx2*)ropetab;
        #pragma unroll
        for (int mi = 0; mi < 8; ++mi) {
            float rn[4];
            #pragma unroll
            for (int r = 0; r < 4; ++r) {
                float ss = 0.0f;
                #pragma unroll
                for (int j = 0; j < 4; ++j) ss += acc[mi][j][r] * acc[mi][j][r];
                ss += __shfl_xor(ss, 1, 64);
                ss += __shfl_xor(ss, 2, 64);
                ss += __shfl_xor(ss, 4, 64);
                ss += __shfl_xor(ss, 8, 64);
                rn[r] = rsqrtf(ss * (1.0f / 64.0f) + 1.1920929e-07f);
            }
            #pragma unroll
            for (int r = 0; r < 4; ++r) {
                int row = m0 + wm * 128 + mi * 16 + quad * 4 + r;
                int t = row & 2047;
                floatx2 cs0 = rtab[t * 32 + lm];        // f = lm      (j=0,2)
                floatx2 cs1 = rtab[t * 32 + 16 + lm];   // f = 16+lm   (j=1,3)
                float g = rn[r];
                #pragma unroll
                for (int j = 0; j < 4; ++j) {
                    int d = j * 16 + lm;
                    float cs = (j & 1) ? cs1[0] : cs0[0];
                    float sn = (j & 1) ? cs1[1] : cs0[1];
                    float v  = acc[mi][j][r] * g;
                    float vp = acc[mi][j ^ 2][r] * g;          // partner d^32
                    float sgn = (d < 32) ? -1.0f : 1.0f;       // (-x2, x1)
                    Cqk[(size_t)row * 2048 + (n0 + wn * 64 + d)] =
                        f2bf((v * cs + sgn * vp * sn) * qsc);
                }
            }
        }
    } else {
        #pragma unroll
        for (int mi = 0; mi < 8; ++mi)
            #pragma unroll
            for (int j = 0; j < 4; ++j) {
                int col  = n0 + wn * 64 + j * 16 + lm;
                int row0 = m0 + wm * 128 + mi * 16 + quad * 4;
                int bq = row0 >> 11, t0 = row0 & 2047;
                ushortx4 pk;
                #pragma unroll
                for (int r = 0; r < 4; ++r) pk[r] = f2bf(acc[mi][j][r]);
                *(ushortx4*)&Vt[((size_t)(bq * 1024 + (col - 2048))) * 2048 + t0] = pk;
            }
    }
#undef TILE
#undef MQ
#undef RD_A
#undef RD_B
#undef STG_A
#undef STG_B
}

// ---------------------------------------------------------------------------
// m97-structure GEMM (proj only). C[M,N] = A[M,K] @ B[N,K]^T.
// ---------------------------------------------------------------------------
template <int BN, int BK>
__global__ __launch_bounds__(256)
void gemm_bt(const unsigned short* __restrict__ A, const unsigned short* __restrict__ B,
             float* __restrict__ Cf, int M, int N, int K)
{
    constexpr int WCOLS = (BN == 128) ? 2 : 1;
    constexpr int WROWS = 4 / WCOLS;
    constexpr int MI    = 128 / (16 * WROWS);
    constexpr int LPR   = BK / 8;
    constexpr int RPI   = 64 / LPR;

    __shared__ __align__(16) unsigned short As[128 * BK];
    __shared__ __align__(16) unsigned short Bs[BN * BK];

    const int tid  = threadIdx.x;
    const int lane = tid & 63;
    const int w    = tid >> 6;
    const int wm   = w / WCOLS, wn = w % WCOLS;
    const int quad = lane >> 4;
    const int lm   = lane & 15;
    const int m0 = blockIdx.y * 128;
    const int n0 = blockIdx.x * BN;
    const int sr = lane / LPR;
    const int sc = (lane % LPR) * 8;

    floatx4 acc[MI][4] = {};

    for (int k0 = 0; k0 < K; k0 += BK) {
        __syncthreads();
        #pragma unroll
        for (int i = 0; i < 32 / RPI; ++i) {
            int r = w * 32 + i * RPI;
            glds16(&A[(size_t)(m0 + r + sr) * K + k0 + sc], &As[r * BK]);
        }
        #pragma unroll
        for (int i = 0; i < (BN / 4) / RPI; ++i) {
            int r = w * (BN / 4) + i * RPI;
            glds16(&B[(size_t)(n0 + r + sr) * K + k0 + sc], &Bs[r * BK]);
        }
        __syncthreads();

        #pragma unroll
        for (int kk = 0; kk < BK / 32; ++kk) {
            bf16x8 a[MI];
            #pragma unroll
            for (int i = 0; i < MI; ++i)
                a[i] = *(const bf16x8*)&As[(wm * (16 * MI) + i * 16 + lm) * BK + kk * 32 + quad * 8];
            #pragma unroll
            for (int j = 0; j < 4; ++j) {
                bf16x8 b = *(const bf16x8*)&Bs[(wn * 64 + j * 16 + lm) * BK + kk * 32 + quad * 8];
                #pragma unroll
                for (int i = 0; i < MI; ++i)
                    acc[i][j] = __builtin_amdgcn_mfma_f32_16x16x32_bf16(a[i], b, acc[i][j], 0, 0, 0);
            }
        }
    }

    #pragma unroll
    for (int i = 0; i < MI; ++i)
        #pragma unroll
        for (int j = 0; j < 4; ++j) {
            int col  = n0 + wn * 64 + j * 16 + lm;
            int row0 = m0 + wm * (16 * MI) + i * 16 + quad * 4;
            #pragma unroll
            for (int r = 0; r < 4; ++r)
                Cf[(size_t)(row0 + r) * N + col] = acc[i][j][r];
        }
}

// ---------------------------------------------------------------------------
// Flash attention, KEY-SPLIT waves. QBLK=64, 256 threads / 4 waves.
// Wave w owns keys w*16..w*16+15 of each 64-key tile:
//   per step LDS reads = 2 K-b128 (its key rows) + 4 V-b64 (its key cols).
// Q: all 4 q-group fragments in registers (loaded once). P: in-register
// (swapped QK^T D-layout == 16x16x16 A-frag; round-7 verified). o: full
// 64x64 key-partial per wave (64 VGPR); cross-wave tree reduction via LDS
// once per block. K/V staged via glds16 with source-XOR swizzle (linear
// dest, rule 21); __syncthreads' vmcnt(0) drain publishes the next buffer.
// softmax: P = exp2(S), scale pre-folded into Q, no max shift (S<=8 bound).
// ---------------------------------------------------------------------------
#define GRP(OT, LT, QT, g, KT, DG)                                             \
  {                                                                            \
    floatx4 sa = {};                                                           \
    sa = __builtin_amdgcn_mfma_f32_16x16x32_bf16(kf0, QT[0], sa, 0, 0, 0);     \
    sa = __builtin_amdgcn_mfma_f32_16x16x32_bf16(kf1, QT[1], sa, 0, 0, 0);     \
    float p0 = exp2f(sa[0]);                                                   \
    float p1 = exp2f(sa[1]);                                                   \
    float p2 = exp2f(sa[2]);                                                   \
    float p3 = exp2f(sa[3]);                                                   \
    if (DG) {                                                                  \
      int kb = (KT) * 64 + w * 16 + quad * 4;                                  \
      int qr = q0 + (g) * 16 + lm;                                             \
      if (kb + 0 > qr) p0 = 0.0f;                                              \
      if (kb + 1 > qr) p1 = 0.0f;                                              \
      if (kb + 2 > qr) p2 = 0.0f;                                              \
      if (kb + 3 > qr) p3 = 0.0f;                                              \
    }                                                                          \
    uintx2 pk;                                                                 \
    pk[0] = pkbf2(p0, p1);                                                     \
    pk[1] = pkbf2(p2, p3);                                                     \
    bf16x4 pa = __builtin_bit_cast(bf16x4, pk);                                \
    LT = __builtin_amdgcn_mfma_f32_16x16x16bf16_1k(pa, ones4, LT, 0, 0, 0);    \
    OT[0] = __builtin_amdgcn_mfma_f32_16x16x16bf16_1k(pa, vb0, OT[0], 0, 0, 0);\
    OT[1] = __builtin_amdgcn_mfma_f32_16x16x16bf16_1k(pa, vb1, OT[1], 0, 0, 0);\
    OT[2] = __builtin_amdgcn_mfma_f32_16x16x16bf16_1k(pa, vb2, OT[2], 0, 0, 0);\
    OT[3] = __builtin_amdgcn_mfma_f32_16x16x16bf16_1k(pa, vb3, OT[3], 0, 0, 0);\
  }

#define ATTN_STEP(KS, VS, KSn, VSn, KT, DG, LAST)                              \
  do {                                                                         \
    if (!(LAST)) {                                                             \
      const size_t tn = (size_t)((KT) + 1);                                    \
      glds16(kg + tn * 131072,         (KSn) + w * 512);                       \
      glds16(kg + tn * 131072 + 65536, (KSn) + 2048 + w * 512);                \
      glds16(vg + tn * 64,             (VSn) + w * 512);                       \
      glds16(vg + tn * 64 + 65536,     (VSn) + 2048 + w * 512);                \
    }                                                                          \
    bf16x8 kf0 = *(const bf16x8*)&(KS)[kfo0];                                  \
    bf16x8 kf1 = *(const bf16x8*)&(KS)[kfo1];                                  \
    bf16x4 vb0 = *(const bf16x4*)&(VS)[vbo0];                                  \
    bf16x4 vb1 = *(const bf16x4*)&(VS)[vbo1];                                  \
    bf16x4 vb2 = *(const bf16x4*)&(VS)[vbo2];                                  \
    bf16x4 vb3 = *(const bf16x4*)&(VS)[vbo3];                                  \
    GRP(oA, lA, qfA, 0, KT, DG)                                                \
    GRP(oB, lB, qfB, 1, KT, DG)                                                \
    GRP(oC, lC, qfC, 2, KT, DG)                                                \
    GRP(oD, lD, qfD, 3, KT, DG)                                                \
    if (!(LAST)) __syncthreads();                                              \
  } while (0)

#define OWR1(S, OT, g)                                                         \
  _Pragma("unroll")                                                            \
  for (int jd = 0; jd < 4; ++jd)                                               \
    _Pragma("unroll")                                                          \
    for (int r = 0; r < 4; ++r)                                                \
      (S)[((g) * 16 + quad * 4 + r) * 64 + jd * 16 + lm] = OT[jd][r];
#define OWR(S) { OWR1(S, oA, 0) OWR1(S, oB, 1) OWR1(S, oC, 2) OWR1(S, oD, 3) }
#define OAC1(S, OT, g)                                                         \
  _Pragma("unroll")                                                            \
  for (int jd = 0; jd < 4; ++jd)                                               \
    _Pragma("unroll")                                                          \
    for (int r = 0; r < 4; ++r)                                                \
      OT[jd][r] += (S)[((g) * 16 + quad * 4 + r) * 64 + jd * 16 + lm];
#define OAC(S) { OAC1(S, oA, 0) OAC1(S, oB, 1) OAC1(S, oC, 2) OAC1(S, oD, 3) }

#define YWR(OT, g)                                                             \
  {                                                                            \
    float rv[4];                                                               \
    _Pragma("unroll")                                                          \
    for (int r = 0; r < 4; ++r) {                                              \
      int qi = (g) * 16 + quad * 4 + r;                                        \
      rv[r] = 1.0f / (lsc[qi] + lsc[64 + qi] + lsc[128 + qi] + lsc[192 + qi]); \
    }                                                                          \
    _Pragma("unroll")                                                          \
    for (int jd = 0; jd < 4; ++jd)                                             \
      _Pragma("unroll")                                                        \
      for (int r = 0; r < 4; ++r)                                              \
        Y[((size_t)(b * 2048 + q0 + (g) * 16 + quad * 4 + r)) * 1024 +         \
          h * 64 + jd * 16 + lm] = f2bf(OT[jd][r] * rv[r]);                    \
  }

__global__ __launch_bounds__(256, 2)
void attention(const unsigned short* __restrict__ qk,
               const unsigned short* __restrict__ Vt,
               unsigned short* __restrict__ Y)
{
    // 40 KiB: QPs(8K) | Ks0(8K) | Ks1(8K) | Vs0(8K) | Vs1(8K)
    __shared__ __align__(16) unsigned short smem[20480];
    unsigned short* const QPs = smem;
    unsigned short* const Ks0 = smem + 4096;
    unsigned short* const Ks1 = smem + 8192;
    unsigned short* const Vs0 = smem + 12288;
    unsigned short* const Vs1 = smem + 16384;
    float* const lsc  = (float*)smem;            // reduction: l (1KB, over QPs)
    float* const ScrA = (float*)(smem + 4096);   // reduction: o (16KB, Ks0+Ks1)
    float* const ScrB = (float*)(smem + 12288);  // reduction: o (16KB, Vs0+Vs1)

    const int tid  = threadIdx.x;
    const int lane = tid & 63;
    const int w    = tid >> 6;           // wave = key-slice owner
    const int quad = lane >> 4;
    const int lm   = lane & 15;
    const int sx   = lm & 7;

    const int bh = blockIdx.x;
    const int qt = 31 - blockIdx.y;      // longest first
    const int b  = bh >> 4, h = bh & 15;
    const int q0 = qt * 64;

    // fragment read offsets (ushort idx), XOR-swizzled chunks
    const int kfo0 = (w * 16 + lm) * 64 + ((quad)     ^ sx) * 8;
    const int kfo1 = (w * 16 + lm) * 64 + ((4 + quad) ^ sx) * 8;
    const int vch  = (w * 2 + (quad >> 1)) ^ sx;
    const int vbo0 = (0 * 16 + lm) * 64 + vch * 8 + (quad & 1) * 4;
    const int vbo1 = (1 * 16 + lm) * 64 + vch * 8 + (quad & 1) * 4;
    const int vbo2 = (2 * 16 + lm) * 64 + vch * 8 + (quad & 1) * 4;
    const int vbo3 = (3 * 16 + lm) * 64 + vch * 8 + (quad & 1) * 4;

    // staging sources (per-lane, source-col XOR so swizzled reads see orig data)
    const int srow = tid >> 3;           // 0..31 (and +32 for 2nd batch)
    const int scol = ((tid & 7) ^ (srow & 7)) * 8;
    const unsigned short* kg = qk + (size_t)b * 4194304 + 1024 + h * 64
                             + (size_t)srow * 2048 + scol;
    const unsigned short* vg = Vt + (size_t)bh * 131072 + (size_t)srow * 2048 + scol;
    const unsigned short* qg = qk + ((size_t)(b * 2048 + q0 + srow)) * 2048
                             + h * 64 + scol;

    // prologue: stage Q + tile 0 (glds; barrier drains vmcnt)
    glds16(qg,         QPs + w * 512);
    glds16(qg + 65536, QPs + 2048 + w * 512);
    glds16(kg,         Ks0 + w * 512);
    glds16(kg + 65536, Ks0 + 2048 + w * 512);
    glds16(vg,         Vs0 + w * 512);
    glds16(vg + 65536, Vs0 + 2048 + w * 512);
    __syncthreads();

    // all 4 q-group fragments in registers (read once)
    bf16x8 qfA[2], qfB[2], qfC[2], qfD[2];
    #pragma unroll
    for (int kk = 0; kk < 2; ++kk) {
        qfA[kk] = *(const bf16x8*)&QPs[(0 * 16 + lm) * 64 + ((kk * 4 + quad) ^ sx) * 8];
        qfB[kk] = *(const bf16x8*)&QPs[(1 * 16 + lm) * 64 + ((kk * 4 + quad) ^ sx) * 8];
        qfC[kk] = *(const bf16x8*)&QPs[(2 * 16 + lm) * 64 + ((kk * 4 + quad) ^ sx) * 8];
        qfD[kk] = *(const bf16x8*)&QPs[(3 * 16 + lm) * 64 + ((kk * 4 + quad) ^ sx) * 8];
    }

    bf16x4 ones4;
    #pragma unroll
    for (int i = 0; i < 4; ++i) ones4[i] = (short)0x3F80;   // bf16 1.0

    floatx4 oA[4] = {}, oB[4] = {}, oC[4] = {}, oD[4] = {};
    floatx4 lA = {}, lB = {}, lC = {}, lD = {};

    // steps 0..qt; static buffer parity; only the final tile is masked.
    int kt = 0;
    for (; kt + 1 < qt; kt += 2) {
        ATTN_STEP(Ks0, Vs0, Ks1, Vs1, kt,     false, false);
        ATTN_STEP(Ks1, Vs1, Ks0, Vs0, kt + 1, false, false);
    }
    if (kt < qt) {                       // qt odd: one more mask-free, diag in buf1
        ATTN_STEP(Ks0, Vs0, Ks1, Vs1, kt, false, false);
        ATTN_STEP(Ks1, Vs1, Ks0, Vs0, qt, true, true);
    } else {                             // qt even: diag in buf0
        ATTN_STEP(Ks0, Vs0, Ks1, Vs1, qt, true, true);
    }

    // ---- cross-wave o/l reduction (once per block) ----
    __syncthreads();                     // all steps done; buffers reusable
    if (lm == 0) {
        #pragma unroll
        for (int r = 0; r < 4; ++r) {
            lsc[w * 64 +  0 + quad * 4 + r] = lA[r];
            lsc[w * 64 + 16 + quad * 4 + r] = lB[r];
            lsc[w * 64 + 32 + quad * 4 + r] = lC[r];
            lsc[w * 64 + 48 + quad * 4 + r] = lD[r];
        }
    }
    if (w == 1) { OWR(ScrA) }
    if (w == 3) { OWR(ScrB) }
    __syncthreads();
    if (w == 0) { OAC(ScrA) }
    if (w == 2) { OAC(ScrB) }
    __syncthreads();
    if (w == 2) { OWR(ScrA) }
    __syncthreads();
    if (w == 0) {
        OAC(ScrA)
        YWR(oA, 0)
        YWR(oB, 1)
        YWR(oC, 2)
        YWR(oD, 3)
    }
}

// ---------------------------------------------------------------------------
extern "C" void kernel_launch(void* const* d_in, const int* in_sizes, int n_in,
                              void* d_out, int out_size, void* d_ws, size_t ws_size,
                              hipStream_t stream)
{
    const float* x      = (const float*)d_in[0];   // [2,2048,1024] fp32
    const float* w_attn = (const float*)d_in[1];   // [3072,1024] fp32
    const float* w_proj = (const float*)d_in[2];   // [1024,1024] fp32
    float* out = (float*)d_out;                    // [2,2048,1024] fp32

    // ws: qk 16.8MB | Vt 8.4MB | y 8.4MB | wpb 2.1MB  (35.7 MB total)
    unsigned short* qkbuf = (unsigned short*)d_ws;
    unsigned short* Vtb   = qkbuf + (size_t)4096 * 2048;
    unsigned short* y     = Vtb   + (size_t)32 * 64 * 2048;
    unsigned short* wpb   = y     + (size_t)4096 * 1024;
    // d_out doubles as pre-cast scratch (dead before proj writes):
    unsigned short* xb  = (unsigned short*)d_out;             // 8.4MB
    unsigned short* wab = xb + (size_t)4096 * 1024;           // 6.3MB
    float* ropetab = (float*)(wab + (size_t)3072 * 1024);     // 512KB

    dim3 blk(256);
    cast_inputs<<<dim3(1024), blk, 0, stream>>>(x, w_attn, w_proj, xb, wab, wpb, ropetab);
    gemm_qkv_8ph<<<dim3(12, 16), dim3(512), 0, stream>>>(xb, wab, ropetab, qkbuf, Vtb);
    attention<<<dim3(32, 32), blk, 0, stream>>>(qkbuf, Vtb, y);
    gemm_bt<64, 64>
        <<<dim3(16, 32), blk, 0, stream>>>(y, wpb, out, 4096, 1024, 1024);
}